// Round 17
// baseline (274.466 us; speedup 1.0000x reference)
//
#include <hip/hip_runtime.h>
#include <math.h>

#define HWSZ  57600
#define NPIX  460800   // 8*57600

typedef __attribute__((ext_vector_type(8))) short bf16x8;
typedef __attribute__((ext_vector_type(4))) float f32x4;
typedef __attribute__((ext_vector_type(16))) float f32x16;
typedef __attribute__((ext_vector_type(4))) unsigned int u32x4;

__device__ __forceinline__ unsigned short f2b(float f) {
    unsigned int u = __float_as_uint(f);
    unsigned int r = (u + 0x7FFFu + ((u >> 16) & 1u)) >> 16;
    return (unsigned short)r;
}
__device__ __forceinline__ float b2f(unsigned short s) {
    return __uint_as_float(((unsigned int)s) << 16);
}

// xp layout (pair-interleaved): element(c, px) = (c & ~1)*NPIX + px*2 + (c & 1)

// -------- K0: fold BN into conv_in weights --------
// Wp2 bf16 [128][64]: k=0..62 = folded W row, k=63 = folded BIAS (bf16).
__global__ void k_prep(const float* __restrict__ w_in, const float* __restrict__ b_in,
                       const float* __restrict__ gamma, const float* __restrict__ beta,
                       const float* __restrict__ mean,  const float* __restrict__ var,
                       unsigned short* __restrict__ Wp, float* __restrict__ bp,
                       unsigned short* __restrict__ Wp2) {
    int idx = blockIdx.x * 256 + threadIdx.x;
    if (idx < 8192) {                 // 128*64 : stride-64 packed
        int o = idx >> 6, c = idx & 63;
        unsigned short v = 0;
        if (o < 126) {
            float s = gamma[o] * rsqrtf(var[o] + 1e-5f);
            if (c < 63)      v = f2b(w_in[o * 63 + c] * s);
            else             v = f2b(b_in[o] * s + beta[o] - mean[o] * s);  // bias in k=63
        }
        Wp2[idx] = v;
    } else if (idx < 8320) {
        int o = idx - 8192;
        float bv = 0.f;
        if (o < 126) {
            float s = gamma[o] * rsqrtf(var[o] + 1e-5f);
            bv = b_in[o] * s + beta[o] - mean[o] * s;
        }
        bp[o] = bv;
    }
}

// -------- K_proj (MFMA, zero-LDS, bias-in-W, paired dword stores) --------
// block = 256 (wave = 64 px), grid = 1800. B-frags built direct from global;
// x's k=63 B-element = 1.0 so the MFMA accumulates the bias row of W.
__global__ __launch_bounds__(256) void k_projM(const float* __restrict__ x,
                                               const unsigned short* __restrict__ Wp2,
                                               const float* __restrict__ bp,
                                               unsigned short* __restrict__ xp) {
    int tid = threadIdx.x;
    int wv = tid >> 6, l = tid & 63;
    int lr = l & 15, lq = l >> 4;
    int blk = blockIdx.x;
    int b = blk / 225;
    int hw0 = (blk - b * 225) * 256 + wv * 64;
    const float* xb = x + (size_t)b * 63 * HWSZ;

    // W-frags direct from global (stride-64 rows, 16B aligned; L1-hot across blocks)
    bf16x8 wa[8][2];
    #pragma unroll
    for (int ot = 0; ot < 8; ot++)
        #pragma unroll
        for (int ks = 0; ks < 2; ks++)
            wa[ot][ks] = *(const bf16x8*)&Wp2[(ot * 16 + lr) * 64 + ks * 32 + lq * 8];

    const f32x4 zf = {0.f, 0.f, 0.f, 0.f};
    for (int pt = 0; pt < 4; pt++) {
        int px = hw0 + pt * 16 + lr;
        const float* xpx = xb + px;
        bf16x8 xf[2];
        #pragma unroll
        for (int ks = 0; ks < 2; ks++) {
            u32x4 pk;
            #pragma unroll
            for (int jj = 0; jj < 4; jj++) {
                int c0 = ks * 32 + lq * 8 + jj * 2;
                float f0 = xpx[(size_t)c0 * HWSZ];                     // c0 <= 62 always
                float f1 = (c0 + 1 < 63) ? xpx[(size_t)(c0 + 1) * HWSZ] : 1.0f;  // k=63 -> 1.0 (bias)
                pk[jj] = (unsigned int)f2b(f0) | ((unsigned int)f2b(f1) << 16);
            }
            xf[ks] = __builtin_bit_cast(bf16x8, pk);
        }
        size_t pxg = (size_t)b * HWSZ + px;
        #pragma unroll
        for (int ot = 0; ot < 8; ot++) {
            f32x4 acc = __builtin_amdgcn_mfma_f32_16x16x32_bf16(wa[ot][0], xf[0], zf, 0, 0, 0);
            acc = __builtin_amdgcn_mfma_f32_16x16x32_bf16(wa[ot][1], xf[1], acc, 0, 0, 0);
            #pragma unroll
            for (int rp = 0; rp < 2; rp++) {
                int o = ot * 16 + lq * 4 + rp * 2;   // even
                if (o < 126) {
                    unsigned int pk = (unsigned int)f2b(acc[rp * 2]) |
                                      ((unsigned int)f2b(acc[rp * 2 + 1]) << 16);
                    *(unsigned int*)&xp[(size_t)o * NPIX + pxg * 2] = pk;
                }
            }
        }
    }
}

// -------- K1 (MFMA): window attention; XCD-swizzled, cheap staging, MFMA-denominator --------
// grid = 9216 (9216 % 8 == 0: bijective swizzle)
__global__ __launch_bounds__(256) void k_winM(const unsigned short* __restrict__ xp,
                                              unsigned short* __restrict__ ybA) {
    __shared__ __align__(16) unsigned short QP[4][32][40];   // Q then P' (unnormalized)
    __shared__ __align__(16) unsigned short Vtl[4][32][40];  // [ch][tok]; ch 21 = ones (tok<25)
    int bid0 = blockIdx.x;
    int bid = (bid0 & 7) * 1152 + (bid0 >> 3);
    int branch = bid / 4608;
    int r = bid - branch * 4608;
    int b = r / 576;
    int r2 = r - b * 576;
    int wi = r2 / 12;
    int g = r2 - wi * 12;
    int tid = threadIdx.x;
    int wv = tid >> 6, l = tid & 63;
    int ish = branch ? 3 : 0;
    int osh = branch ? 2 : 0;

    for (int i = tid; i < 2560; i += 256) ((unsigned int*)QP)[i] = 0;
    for (int i = tid; i < 2560; i += 256) ((unsigned int*)Vtl)[i] = 0;
    __syncthreads();

    // staging: thread -> FIXED pixel; iterate channels (pair-interleaved xp)
    size_t xbase = (size_t)b * HWSZ;
    if (tid < 200) {
        int co = (tid >= 100) ? 1 : 0;
        int px = tid - co * 100;
        int pr = px / 20, pc20 = px - pr * 20;
        int w = pc20 / 5, tok = pr * 5 + (pc20 - w * 5);
        int ih = wi * 5 + pr + ish; if (ih >= 240) ih -= 240;
        int iw = g * 20 + pc20 + ish; if (iw >= 240) iw -= 240;
        size_t pix = xbase + ih * 240 + iw;
        const unsigned short* src = xp + (size_t)(branch * 42) * NPIX + pix * 2 + co;
        unsigned short* dq = &QP[w][tok][0];
        unsigned short* dv = &Vtl[w][0][tok];
        #pragma unroll
        for (int cc = 0; cc < 21; cc++) {
            int c = co + 2 * cc;
            unsigned short v = src[(size_t)(2 * cc) * NPIX];
            if (c < 21) dq[c] = v;
            else        dv[(c - 21) * 40] = v;
        }
    }
    if (tid < 100) {   // ones row (denominator channel), valid tokens only
        int w = tid / 25, tok = tid - (tid / 25) * 25;
        Vtl[w][21][tok] = 0x3F80;
    }
    __syncthreads();

    int lr32 = l & 31, hi = l >> 5;
    f32x16 z16;
    #pragma unroll
    for (int i = 0; i < 16; i++) z16[i] = 0.f;

    // S = Q Q^T
    bf16x8 a0 = *(const bf16x8*)&QP[wv][lr32][hi * 8];
    bf16x8 a1 = *(const bf16x8*)&QP[wv][lr32][16 + hi * 8];
    f32x16 S = __builtin_amdgcn_mfma_f32_32x32x16_bf16(a0, a0, z16, 0, 0, 0);
    S = __builtin_amdgcn_mfma_f32_32x32x16_bf16(a1, a1, S, 0, 0, 0);

    // P' = exp(S) unnormalized -> LDS (overwrite own Q stripe).
    // |S| <= ~30 << 88 so no max-subtraction needed; pad cols exp(0)=1 x zero V.
    #pragma unroll
    for (int rg = 0; rg < 16; rg++) {
        float e = __expf(S[rg]);
        int row = (rg & 3) + 8 * (rg >> 2) + 4 * hi;
        QP[wv][row][lr32] = f2b(e);
    }

    // Y = P' V ; col 21 = row-sum (denominator)
    bf16x8 pa0 = *(const bf16x8*)&QP[wv][lr32][hi * 8];
    bf16x8 pa1 = *(const bf16x8*)&QP[wv][lr32][16 + hi * 8];
    bf16x8 vb0 = *(const bf16x8*)&Vtl[wv][lr32][hi * 8];
    bf16x8 vb1 = *(const bf16x8*)&Vtl[wv][lr32][16 + hi * 8];
    f32x16 Y = __builtin_amdgcn_mfma_f32_32x32x16_bf16(pa0, vb0, z16, 0, 0, 0);
    Y = __builtin_amdgcn_mfma_f32_32x32x16_bf16(pa1, vb1, Y, 0, 0, 0);

    size_t obb = (size_t)b * HWSZ;
    int wi5 = wi * 5 + osh, g20 = g * 20 + wv * 5 + osh;
    #pragma unroll
    for (int rg = 0; rg < 16; rg++) {
        int tok = (rg & 3) + 8 * (rg >> 2) + 4 * hi;
        if (tok < 25) {
            float den = __shfl(Y[rg], 21, 32);
            float v = Y[rg] * (1.0f / den);
            int pr = tok / 5, pc = tok - (tok / 5) * 5;
            int oh = wi5 + pr; if (oh >= 240) oh -= 240;
            int ow = g20 + pc; if (ow >= 240) ow -= 240;
            if (lr32 < 21)
                ybA[(obb + oh * 240 + ow) * 42 + branch * 21 + lr32] = f2b(v);
        }
    }
}

// -------- MFMA axial attention core (verified round 4) --------
__device__ __forceinline__ void axial_core(const unsigned short* Q, const unsigned short* Vt,
                                           unsigned short* Pl,
                                           unsigned short* outp, size_t obase) {
    int tid = threadIdx.x;
    int wv = tid >> 6, l = tid & 63;
    int lr = l & 15, lq = l >> 4;
    const f32x4 zf = {0.f, 0.f, 0.f, 0.f};
    int m0 = wv * 16;

    for (int mt = 0; mt < 4; mt++) {
        if (mt == 3 && wv == 3) continue;   // tile 15 would be rows 240..255 (OOB)
        int rbase = mt * 64 + wv * 16;
        bf16x8 afr = *(const bf16x8*)&Q[(rbase + lr) * 40 + lq * 8];
        f32x4 d[15];
        #pragma unroll
        for (int jt = 0; jt < 15; jt++) {
            bf16x8 bfr = *(const bf16x8*)&Q[(jt * 16 + lr) * 40 + lq * 8];
            d[jt] = __builtin_amdgcn_mfma_f32_16x16x32_bf16(afr, bfr, zf, 0, 0, 0);
        }
        float mx[4] = {-1e30f, -1e30f, -1e30f, -1e30f};
        #pragma unroll
        for (int jt = 0; jt < 15; jt++)
            #pragma unroll
            for (int r = 0; r < 4; r++) mx[r] = fmaxf(mx[r], d[jt][r]);
        #pragma unroll
        for (int s = 1; s < 16; s <<= 1)
            #pragma unroll
            for (int r = 0; r < 4; r++) mx[r] = fmaxf(mx[r], __shfl_xor(mx[r], s));
        float sm[4] = {0.f, 0.f, 0.f, 0.f};
        #pragma unroll
        for (int jt = 0; jt < 15; jt++)
            #pragma unroll
            for (int r = 0; r < 4; r++) { float e = __expf(d[jt][r] - mx[r]); d[jt][r] = e; sm[r] += e; }
        #pragma unroll
        for (int s = 1; s < 16; s <<= 1)
            #pragma unroll
            for (int r = 0; r < 4; r++) sm[r] += __shfl_xor(sm[r], s);
        float inv[4];
        #pragma unroll
        for (int r = 0; r < 4; r++) inv[r] = 1.0f / sm[r];

        #pragma unroll
        for (int jt = 0; jt < 8; jt++)
            #pragma unroll
            for (int r = 0; r < 4; r++)
                Pl[(m0 + lq * 4 + r) * 136 + jt * 16 + lr] = f2b(d[jt][r] * inv[r]);
        f32x4 y0 = zf, y1 = zf;
        #pragma unroll
        for (int ks = 0; ks < 4; ks++) {
            bf16x8 pa = *(const bf16x8*)&Pl[(m0 + lr) * 136 + ks * 32 + lq * 8];
            bf16x8 v0 = *(const bf16x8*)&Vt[lr * 264 + ks * 32 + lq * 8];
            bf16x8 v1f = *(const bf16x8*)&Vt[(lr + 16) * 264 + ks * 32 + lq * 8];
            y0 = __builtin_amdgcn_mfma_f32_16x16x32_bf16(pa, v0, y0, 0, 0, 0);
            y1 = __builtin_amdgcn_mfma_f32_16x16x32_bf16(pa, v1f, y1, 0, 0, 0);
        }
        #pragma unroll
        for (int jt = 8; jt < 15; jt++)
            #pragma unroll
            for (int r = 0; r < 4; r++)
                Pl[(m0 + lq * 4 + r) * 136 + (jt - 8) * 16 + lr] = f2b(d[jt][r] * inv[r]);
        #pragma unroll
        for (int r = 0; r < 4; r++)
            Pl[(m0 + lq * 4 + r) * 136 + 112 + lr] = 0;
        #pragma unroll
        for (int ks = 0; ks < 4; ks++) {
            bf16x8 pa = *(const bf16x8*)&Pl[(m0 + lr) * 136 + ks * 32 + lq * 8];
            bf16x8 v0 = *(const bf16x8*)&Vt[lr * 264 + (ks + 4) * 32 + lq * 8];
            bf16x8 v1f = *(const bf16x8*)&Vt[(lr + 16) * 264 + (ks + 4) * 32 + lq * 8];
            y0 = __builtin_amdgcn_mfma_f32_16x16x32_bf16(pa, v0, y0, 0, 0, 0);
            y1 = __builtin_amdgcn_mfma_f32_16x16x32_bf16(pa, v1f, y1, 0, 0, 0);
        }
        #pragma unroll
        for (int r = 0; r < 4; r++) {
            int tok = rbase + lq * 4 + r;
            size_t oa = obase + (size_t)tok * 5040;
            outp[oa + lr] = f2b(y0[r]);
            if (lr < 5) outp[oa + 16 + lr] = f2b(y1[r]);
        }
    }
}

// -------- K2: axial stage 1 (tokens along w). grid = 1920 --------
__global__ __launch_bounds__(256) void k_ax1(const unsigned short* __restrict__ xp,
                                             unsigned short* __restrict__ qt,
                                             unsigned short* __restrict__ v1) {
    __shared__ __align__(16) unsigned short Q[240 * 40];
    __shared__ __align__(16) unsigned short Vt[32 * 264];
    __shared__ __align__(16) unsigned short Pl[64 * 136];
    int b = blockIdx.x / 240, h = blockIdx.x % 240;
    int tid = threadIdx.x;
    for (int i = tid; i < 4800; i += 256) ((unsigned int*)Q)[i] = 0;
    for (int i = tid; i < 4224; i += 256) ((unsigned int*)Vt)[i] = 0;
    __syncthreads();
    size_t xb = (size_t)b * HWSZ + h * 240;
    // staging: thread -> fixed w; pair-interleaved xp addressing (compile-time per c)
    if (tid < 240) {
        size_t px2 = (xb + tid) * 2;
        unsigned short* dq = &Q[tid * 40];
        #pragma unroll
        for (int c = 0; c < 21; c++) {
            int cq = 84 + c, cv = 105 + c;
            dq[c]             = xp[(size_t)(cq & ~1) * NPIX + px2 + (cq & 1)];
            Vt[c * 264 + tid] = xp[(size_t)(cv & ~1) * NPIX + px2 + (cv & 1)];
        }
    }
    __syncthreads();
    size_t qtb = (size_t)b * 1209600 + h * 21;
    for (int idx = tid; idx < 5040; idx += 256) {
        int w = idx / 21, c = idx - w * 21;
        qt[qtb + (size_t)w * 5040 + c] = Q[w * 40 + c];
    }
    axial_core(Q, Vt, Pl, v1, (size_t)b * 1209600 + h * 21);
}

// -------- K3: axial stage 2 (tokens along h). grid = 1920 --------
__global__ __launch_bounds__(256) void k_ax2(const unsigned short* __restrict__ qt,
                                             const unsigned short* __restrict__ v1,
                                             unsigned short* __restrict__ ybB) {
    __shared__ __align__(16) unsigned short Q[240 * 40];
    __shared__ __align__(16) unsigned short Vt[32 * 264];
    __shared__ __align__(16) unsigned short Pl[64 * 136];
    int b = blockIdx.x / 240, w = blockIdx.x % 240;
    int tid = threadIdx.x;
    for (int i = tid; i < 4800; i += 256) ((unsigned int*)Q)[i] = 0;
    for (int i = tid; i < 4224; i += 256) ((unsigned int*)Vt)[i] = 0;
    __syncthreads();
    size_t base = ((size_t)b * 240 + w) * 5040;
    for (int idx = tid; idx < 5040; idx += 256) {
        int h = idx / 21, c = idx - h * 21;
        Q[h * 40 + c]   = qt[base + idx];
        Vt[c * 264 + h] = v1[base + idx];
    }
    __syncthreads();
    axial_core(Q, Vt, Pl, ybB, (size_t)b * 1209600 + w * 21);
}

// -------- K4 (MFMA): conv_out. M=64 out-ch, N=256 px, K=64 --------
__global__ __launch_bounds__(256) void k_outM(const unsigned short* __restrict__ ybA,
                                              const unsigned short* __restrict__ ybB,
                                              const float* __restrict__ w_out,
                                              const float* __restrict__ b_out,
                                              float* __restrict__ out) {
    __shared__ __align__(16) unsigned short Yl[256][72];
    __shared__ __align__(16) unsigned short Wo[64][72];
    __shared__ float bl[64];
    int tid = threadIdx.x;
    int pg = blockIdx.x * 256 + tid;

    for (int i = tid; i < 64 * 36; i += 256) ((unsigned int*)Wo)[i] = 0;
    __syncthreads();
    {
        const unsigned int* a32 = (const unsigned int*)(ybA + (size_t)pg * 42);
        unsigned short* yr = Yl[tid];
        #pragma unroll
        for (int c = 0; c < 21; c++) *(unsigned int*)&yr[c * 2] = a32[c];
        const unsigned short* bb2 = ybB + (size_t)pg * 21;
        #pragma unroll
        for (int c = 0; c < 21; c++) yr[42 + c] = bb2[c];
        #pragma unroll
        for (int c = 63; c < 72; c++) yr[c] = 0;
    }
    for (int idx = tid; idx < 3969; idx += 256) {
        int o = idx / 63, c = idx - o * 63;
        Wo[o][c] = f2b(w_out[idx]);
    }
    if (tid < 64) bl[tid] = (tid < 63) ? b_out[tid] : 0.f;
    __syncthreads();

    int wv = tid >> 6, l = tid & 63;
    int lr = l & 15, lq = l >> 4;
    const f32x4 zf = {0.f, 0.f, 0.f, 0.f};
    bf16x8 wa[4][2];
    #pragma unroll
    for (int ot = 0; ot < 4; ot++)
        #pragma unroll
        for (int ks = 0; ks < 2; ks++)
            wa[ot][ks] = *(const bf16x8*)&Wo[ot * 16 + lr][ks * 32 + lq * 8];

    int p0 = blockIdx.x * 256;
    int b = p0 / HWSZ;
    int hwb = p0 - b * HWSZ;
    for (int pt = 0; pt < 4; pt++) {
        int prow = (wv * 4 + pt) * 16;
        bf16x8 y0 = *(const bf16x8*)&Yl[prow + lr][lq * 8];
        bf16x8 y1 = *(const bf16x8*)&Yl[prow + lr][32 + lq * 8];
        f32x4 acc[4];
        #pragma unroll
        for (int ot = 0; ot < 4; ot++) {
            acc[ot] = __builtin_amdgcn_mfma_f32_16x16x32_bf16(wa[ot][0], y0, zf, 0, 0, 0);
            acc[ot] = __builtin_amdgcn_mfma_f32_16x16x32_bf16(wa[ot][1], y1, acc[ot], 0, 0, 0);
        }
        int hw = hwb + prow + lr;
        #pragma unroll
        for (int ot = 0; ot < 4; ot++) {
            #pragma unroll
            for (int r = 0; r < 4; r++) {
                int o = ot * 16 + lq * 4 + r;
                if (o < 63)
                    out[((size_t)(b * 63 + o)) * HWSZ + hw] = acc[ot][r] + bl[o];
            }
        }
    }
}

extern "C" void kernel_launch(void* const* d_in, const int* in_sizes, int n_in,
                              void* d_out, int out_size, void* d_ws, size_t ws_size,
                              hipStream_t stream) {
    const float* x     = (const float*)d_in[0];
    const float* w_in  = (const float*)d_in[1];
    const float* b_in  = (const float*)d_in[2];
    const float* gamma = (const float*)d_in[3];
    const float* beta  = (const float*)d_in[4];
    const float* mean  = (const float*)d_in[5];
    const float* var   = (const float*)d_in[6];
    const float* w_out = (const float*)d_in[7];
    const float* b_out = (const float*)d_in[8];
    float* out = (float*)d_out;

    char* ws = (char*)d_ws;
    unsigned short* xp  = (unsigned short*)ws;                 // bf16 pair-interleaved [63pair][NPIX][2]
    unsigned short* ybA = (unsigned short*)(ws + 116121600);   // bf16 [NPIX][42]
    unsigned short* Wp  = (unsigned short*)(ws + 154828800);   // bf16 [128][66] (legacy)
    float*          bp  = (float*)(ws + 154845696);            // f32 [128]
    unsigned short* Wp2 = (unsigned short*)(ws + 154846208);   // bf16 [128][64]; k=63 = bias
    unsigned short* qt  = (unsigned short*)ws;                 // alias xp pairs (dead after k_winM)
    unsigned short* v1  = (unsigned short*)(ws + 19353600);
    unsigned short* ybB = (unsigned short*)(ws + 38707200);

    k_prep <<<34, 256, 0, stream>>>(w_in, b_in, gamma, beta, mean, var, Wp, bp, Wp2);
    k_projM<<<1800, 256, 0, stream>>>(x, Wp2, bp, xp);
    k_winM <<<9216, 256, 0, stream>>>(xp, ybA);
    k_ax1  <<<1920, 256, 0, stream>>>(xp, qt, v1);
    k_ax2  <<<1920, 256, 0, stream>>>(qt, v1, ybB);
    k_outM <<<1800, 256, 0, stream>>>(ybA, ybB, w_out, b_out, out);
}

// Round 18
// 263.032 us; speedup vs baseline: 1.0435x; 1.0435x over previous
//
#include <hip/hip_runtime.h>
#include <math.h>

#define HWSZ  57600
#define NPIX  460800   // 8*57600

typedef __attribute__((ext_vector_type(8))) short bf16x8;
typedef __attribute__((ext_vector_type(4))) float f32x4;
typedef __attribute__((ext_vector_type(16))) float f32x16;
typedef __attribute__((ext_vector_type(4))) unsigned int u32x4;

__device__ __forceinline__ unsigned short f2b(float f) {
    unsigned int u = __float_as_uint(f);
    unsigned int r = (u + 0x7FFFu + ((u >> 16) & 1u)) >> 16;
    return (unsigned short)r;
}
__device__ __forceinline__ float b2f(unsigned short s) {
    return __uint_as_float(((unsigned int)s) << 16);
}

// xp layout (pair-interleaved): element(c, px) = (c & ~1)*NPIX + px*2 + (c & 1)

// -------- K0: fold BN into conv_in weights --------
__global__ void k_prep(const float* __restrict__ w_in, const float* __restrict__ b_in,
                       const float* __restrict__ gamma, const float* __restrict__ beta,
                       const float* __restrict__ mean,  const float* __restrict__ var,
                       unsigned short* __restrict__ Wp, float* __restrict__ bp,
                       unsigned short* __restrict__ Wp2) {
    int idx = blockIdx.x * 256 + threadIdx.x;
    if (idx < 8192) {                 // 128*64 : stride-64 packed
        int o = idx >> 6, c = idx & 63;
        unsigned short v = 0;
        if (o < 126 && c < 63) {
            float s = gamma[o] * rsqrtf(var[o] + 1e-5f);
            v = f2b(w_in[o * 63 + c] * s);
        }
        Wp2[idx] = v;
    } else if (idx < 8320) {
        int o = idx - 8192;
        float bv = 0.f;
        if (o < 126) {
            float s = gamma[o] * rsqrtf(var[o] + 1e-5f);
            bv = b_in[o] * s + beta[o] - mean[o] * s;
        }
        bp[o] = bv;
    }
}

// -------- K_proj (MFMA, round-16 measured-best: staged Xl, barrier-free, paired stores) --------
#define XS 66
__global__ __launch_bounds__(256) void k_projM(const float* __restrict__ x,
                                               const unsigned short* __restrict__ Wp2,
                                               const float* __restrict__ bp,
                                               unsigned short* __restrict__ xp) {
    __shared__ __align__(16) unsigned short Xl[256 * XS];   // [pixel][k] bf16, k=63 zero
    int blk = blockIdx.x;
    int tid = threadIdx.x;
    int b = blk / 225;
    int hw0 = (blk - b * 225) * 256;
    int wv = tid >> 6, l = tid & 63;
    int lr = l & 15, lq = l >> 4;

    // stage own pixel (wave-local LDS quarter)
    {
        const float* xb = x + (size_t)b * 63 * HWSZ + hw0 + tid;
        unsigned short* xr = &Xl[tid * XS];
        #pragma unroll
        for (int c = 0; c < 62; c += 2) {
            unsigned int lo = f2b(xb[(size_t)c * HWSZ]);
            unsigned int hi = f2b(xb[(size_t)(c + 1) * HWSZ]);
            *(unsigned int*)&xr[c] = lo | (hi << 16);
        }
        unsigned int lo = f2b(xb[(size_t)62 * HWSZ]);
        *(unsigned int*)&xr[62] = lo;   // k=63 zeroed
    }

    // W-frags direct from global (stride-64 rows, 16B aligned; L1-hot across blocks)
    bf16x8 wa[8][2];
    #pragma unroll
    for (int ot = 0; ot < 8; ot++)
        #pragma unroll
        for (int ks = 0; ks < 2; ks++)
            wa[ot][ks] = *(const bf16x8*)&Wp2[(ot * 16 + lr) * 64 + ks * 32 + lq * 8];
    f32x4 bias[8];
    #pragma unroll
    for (int ot = 0; ot < 8; ot++)
        bias[ot] = *(const f32x4*)&bp[ot * 16 + lq * 4];

    for (int pt = 0; pt < 4; pt++) {
        int prow = (wv * 4 + pt) * 16;
        bf16x8 xb0 = *(const bf16x8*)&Xl[(prow + lr) * XS + lq * 8];
        bf16x8 xb1 = *(const bf16x8*)&Xl[(prow + lr) * XS + 32 + lq * 8];
        f32x4 acc[8];
        #pragma unroll
        for (int ot = 0; ot < 8; ot++) {
            acc[ot] = __builtin_amdgcn_mfma_f32_16x16x32_bf16(wa[ot][0], xb0, bias[ot], 0, 0, 0);
            acc[ot] = __builtin_amdgcn_mfma_f32_16x16x32_bf16(wa[ot][1], xb1, acc[ot], 0, 0, 0);
        }
        size_t px = (size_t)b * HWSZ + hw0 + prow + lr;
        #pragma unroll
        for (int ot = 0; ot < 8; ot++) {
            #pragma unroll
            for (int rp = 0; rp < 2; rp++) {
                int o = ot * 16 + lq * 4 + rp * 2;   // even
                if (o < 126) {
                    unsigned int pk = (unsigned int)f2b(acc[ot][rp * 2]) |
                                      ((unsigned int)f2b(acc[ot][rp * 2 + 1]) << 16);
                    *(unsigned int*)&xp[(size_t)o * NPIX + px * 2] = pk;
                }
            }
        }
    }
}

// -------- K1 (MFMA): window attention; XCD-swizzled, cheap staging, MFMA-denominator --------
// grid = 9216 (9216 % 8 == 0: bijective swizzle)
__global__ __launch_bounds__(256) void k_winM(const unsigned short* __restrict__ xp,
                                              unsigned short* __restrict__ ybA) {
    __shared__ __align__(16) unsigned short QP[4][32][40];   // Q then P' (unnormalized)
    __shared__ __align__(16) unsigned short Vtl[4][32][40];  // [ch][tok]; ch 21 = ones (tok<25)
    int bid0 = blockIdx.x;
    int bid = (bid0 & 7) * 1152 + (bid0 >> 3);
    int branch = bid / 4608;
    int r = bid - branch * 4608;
    int b = r / 576;
    int r2 = r - b * 576;
    int wi = r2 / 12;
    int g = r2 - wi * 12;
    int tid = threadIdx.x;
    int wv = tid >> 6, l = tid & 63;
    int ish = branch ? 3 : 0;
    int osh = branch ? 2 : 0;

    for (int i = tid; i < 2560; i += 256) ((unsigned int*)QP)[i] = 0;
    for (int i = tid; i < 2560; i += 256) ((unsigned int*)Vtl)[i] = 0;
    __syncthreads();

    // staging: thread -> FIXED pixel; iterate channels (pair-interleaved xp)
    size_t xbase = (size_t)b * HWSZ;
    if (tid < 200) {
        int co = (tid >= 100) ? 1 : 0;
        int px = tid - co * 100;
        int pr = px / 20, pc20 = px - pr * 20;
        int w = pc20 / 5, tok = pr * 5 + (pc20 - w * 5);
        int ih = wi * 5 + pr + ish; if (ih >= 240) ih -= 240;
        int iw = g * 20 + pc20 + ish; if (iw >= 240) iw -= 240;
        size_t pix = xbase + ih * 240 + iw;
        const unsigned short* src = xp + (size_t)(branch * 42) * NPIX + pix * 2 + co;
        unsigned short* dq = &QP[w][tok][0];
        unsigned short* dv = &Vtl[w][0][tok];
        #pragma unroll
        for (int cc = 0; cc < 21; cc++) {
            int c = co + 2 * cc;
            unsigned short v = src[(size_t)(2 * cc) * NPIX];
            if (c < 21) dq[c] = v;
            else        dv[(c - 21) * 40] = v;
        }
    }
    if (tid < 100) {   // ones row (denominator channel), valid tokens only
        int w = tid / 25, tok = tid - (tid / 25) * 25;
        Vtl[w][21][tok] = 0x3F80;
    }
    __syncthreads();

    int lr32 = l & 31, hi = l >> 5;
    f32x16 z16;
    #pragma unroll
    for (int i = 0; i < 16; i++) z16[i] = 0.f;

    // S = Q Q^T
    bf16x8 a0 = *(const bf16x8*)&QP[wv][lr32][hi * 8];
    bf16x8 a1 = *(const bf16x8*)&QP[wv][lr32][16 + hi * 8];
    f32x16 S = __builtin_amdgcn_mfma_f32_32x32x16_bf16(a0, a0, z16, 0, 0, 0);
    S = __builtin_amdgcn_mfma_f32_32x32x16_bf16(a1, a1, S, 0, 0, 0);

    // P' = exp(S) unnormalized -> LDS (overwrite own Q stripe).
    // |S| <= ~30 << 88 so no max-subtraction needed; pad cols exp(0)=1 x zero V.
    #pragma unroll
    for (int rg = 0; rg < 16; rg++) {
        float e = __expf(S[rg]);
        int row = (rg & 3) + 8 * (rg >> 2) + 4 * hi;
        QP[wv][row][lr32] = f2b(e);
    }

    // Y = P' V ; col 21 = row-sum (denominator)
    bf16x8 pa0 = *(const bf16x8*)&QP[wv][lr32][hi * 8];
    bf16x8 pa1 = *(const bf16x8*)&QP[wv][lr32][16 + hi * 8];
    bf16x8 vb0 = *(const bf16x8*)&Vtl[wv][lr32][hi * 8];
    bf16x8 vb1 = *(const bf16x8*)&Vtl[wv][lr32][16 + hi * 8];
    f32x16 Y = __builtin_amdgcn_mfma_f32_32x32x16_bf16(pa0, vb0, z16, 0, 0, 0);
    Y = __builtin_amdgcn_mfma_f32_32x32x16_bf16(pa1, vb1, Y, 0, 0, 0);

    size_t obb = (size_t)b * HWSZ;
    int wi5 = wi * 5 + osh, g20 = g * 20 + wv * 5 + osh;
    #pragma unroll
    for (int rg = 0; rg < 16; rg++) {
        int tok = (rg & 3) + 8 * (rg >> 2) + 4 * hi;
        if (tok < 25) {
            float den = __shfl(Y[rg], 21, 32);
            float v = Y[rg] * (1.0f / den);
            int pr = tok / 5, pc = tok - (tok / 5) * 5;
            int oh = wi5 + pr; if (oh >= 240) oh -= 240;
            int ow = g20 + pc; if (ow >= 240) ow -= 240;
            if (lr32 < 21)
                ybA[(obb + oh * 240 + ow) * 42 + branch * 21 + lr32] = f2b(v);
        }
    }
}

// -------- MFMA axial attention core (verified round 4) --------
__device__ __forceinline__ void axial_core(const unsigned short* Q, const unsigned short* Vt,
                                           unsigned short* Pl,
                                           unsigned short* outp, size_t obase) {
    int tid = threadIdx.x;
    int wv = tid >> 6, l = tid & 63;
    int lr = l & 15, lq = l >> 4;
    const f32x4 zf = {0.f, 0.f, 0.f, 0.f};
    int m0 = wv * 16;

    for (int mt = 0; mt < 4; mt++) {
        if (mt == 3 && wv == 3) continue;   // tile 15 would be rows 240..255 (OOB)
        int rbase = mt * 64 + wv * 16;
        bf16x8 afr = *(const bf16x8*)&Q[(rbase + lr) * 40 + lq * 8];
        f32x4 d[15];
        #pragma unroll
        for (int jt = 0; jt < 15; jt++) {
            bf16x8 bfr = *(const bf16x8*)&Q[(jt * 16 + lr) * 40 + lq * 8];
            d[jt] = __builtin_amdgcn_mfma_f32_16x16x32_bf16(afr, bfr, zf, 0, 0, 0);
        }
        float mx[4] = {-1e30f, -1e30f, -1e30f, -1e30f};
        #pragma unroll
        for (int jt = 0; jt < 15; jt++)
            #pragma unroll
            for (int r = 0; r < 4; r++) mx[r] = fmaxf(mx[r], d[jt][r]);
        #pragma unroll
        for (int s = 1; s < 16; s <<= 1)
            #pragma unroll
            for (int r = 0; r < 4; r++) mx[r] = fmaxf(mx[r], __shfl_xor(mx[r], s));
        float sm[4] = {0.f, 0.f, 0.f, 0.f};
        #pragma unroll
        for (int jt = 0; jt < 15; jt++)
            #pragma unroll
            for (int r = 0; r < 4; r++) { float e = __expf(d[jt][r] - mx[r]); d[jt][r] = e; sm[r] += e; }
        #pragma unroll
        for (int s = 1; s < 16; s <<= 1)
            #pragma unroll
            for (int r = 0; r < 4; r++) sm[r] += __shfl_xor(sm[r], s);
        float inv[4];
        #pragma unroll
        for (int r = 0; r < 4; r++) inv[r] = 1.0f / sm[r];

        #pragma unroll
        for (int jt = 0; jt < 8; jt++)
            #pragma unroll
            for (int r = 0; r < 4; r++)
                Pl[(m0 + lq * 4 + r) * 136 + jt * 16 + lr] = f2b(d[jt][r] * inv[r]);
        f32x4 y0 = zf, y1 = zf;
        #pragma unroll
        for (int ks = 0; ks < 4; ks++) {
            bf16x8 pa = *(const bf16x8*)&Pl[(m0 + lr) * 136 + ks * 32 + lq * 8];
            bf16x8 v0 = *(const bf16x8*)&Vt[lr * 264 + ks * 32 + lq * 8];
            bf16x8 v1f = *(const bf16x8*)&Vt[(lr + 16) * 264 + ks * 32 + lq * 8];
            y0 = __builtin_amdgcn_mfma_f32_16x16x32_bf16(pa, v0, y0, 0, 0, 0);
            y1 = __builtin_amdgcn_mfma_f32_16x16x32_bf16(pa, v1f, y1, 0, 0, 0);
        }
        #pragma unroll
        for (int jt = 8; jt < 15; jt++)
            #pragma unroll
            for (int r = 0; r < 4; r++)
                Pl[(m0 + lq * 4 + r) * 136 + (jt - 8) * 16 + lr] = f2b(d[jt][r] * inv[r]);
        #pragma unroll
        for (int r = 0; r < 4; r++)
            Pl[(m0 + lq * 4 + r) * 136 + 112 + lr] = 0;
        #pragma unroll
        for (int ks = 0; ks < 4; ks++) {
            bf16x8 pa = *(const bf16x8*)&Pl[(m0 + lr) * 136 + ks * 32 + lq * 8];
            bf16x8 v0 = *(const bf16x8*)&Vt[lr * 264 + (ks + 4) * 32 + lq * 8];
            bf16x8 v1f = *(const bf16x8*)&Vt[(lr + 16) * 264 + (ks + 4) * 32 + lq * 8];
            y0 = __builtin_amdgcn_mfma_f32_16x16x32_bf16(pa, v0, y0, 0, 0, 0);
            y1 = __builtin_amdgcn_mfma_f32_16x16x32_bf16(pa, v1f, y1, 0, 0, 0);
        }
        #pragma unroll
        for (int r = 0; r < 4; r++) {
            int tok = rbase + lq * 4 + r;
            size_t oa = obase + (size_t)tok * 5040;
            outp[oa + lr] = f2b(y0[r]);
            if (lr < 5) outp[oa + 16 + lr] = f2b(y1[r]);
        }
    }
}

// -------- K2: axial stage 1 (tokens along w). grid = 1920 --------
__global__ __launch_bounds__(256) void k_ax1(const unsigned short* __restrict__ xp,
                                             unsigned short* __restrict__ qt,
                                             unsigned short* __restrict__ v1) {
    __shared__ __align__(16) unsigned short Q[240 * 40];
    __shared__ __align__(16) unsigned short Vt[32 * 264];
    __shared__ __align__(16) unsigned short Pl[64 * 136];
    int b = blockIdx.x / 240, h = blockIdx.x % 240;
    int tid = threadIdx.x;
    for (int i = tid; i < 4800; i += 256) ((unsigned int*)Q)[i] = 0;
    for (int i = tid; i < 4224; i += 256) ((unsigned int*)Vt)[i] = 0;
    __syncthreads();
    size_t xb = (size_t)b * HWSZ + h * 240;
    // staging: thread -> fixed w; pair-interleaved xp addressing (compile-time per c)
    if (tid < 240) {
        size_t px2 = (xb + tid) * 2;
        unsigned short* dq = &Q[tid * 40];
        #pragma unroll
        for (int c = 0; c < 21; c++) {
            int cq = 84 + c, cv = 105 + c;
            dq[c]             = xp[(size_t)(cq & ~1) * NPIX + px2 + (cq & 1)];
            Vt[c * 264 + tid] = xp[(size_t)(cv & ~1) * NPIX + px2 + (cv & 1)];
        }
    }
    __syncthreads();
    size_t qtb = (size_t)b * 1209600 + h * 21;
    for (int idx = tid; idx < 5040; idx += 256) {
        int w = idx / 21, c = idx - w * 21;
        qt[qtb + (size_t)w * 5040 + c] = Q[w * 40 + c];
    }
    axial_core(Q, Vt, Pl, v1, (size_t)b * 1209600 + h * 21);
}

// -------- K3: axial stage 2 (tokens along h). grid = 1920 --------
__global__ __launch_bounds__(256) void k_ax2(const unsigned short* __restrict__ qt,
                                             const unsigned short* __restrict__ v1,
                                             unsigned short* __restrict__ ybB) {
    __shared__ __align__(16) unsigned short Q[240 * 40];
    __shared__ __align__(16) unsigned short Vt[32 * 264];
    __shared__ __align__(16) unsigned short Pl[64 * 136];
    int b = blockIdx.x / 240, w = blockIdx.x % 240;
    int tid = threadIdx.x;
    for (int i = tid; i < 4800; i += 256) ((unsigned int*)Q)[i] = 0;
    for (int i = tid; i < 4224; i += 256) ((unsigned int*)Vt)[i] = 0;
    __syncthreads();
    size_t base = ((size_t)b * 240 + w) * 5040;
    // staging: thread -> fixed token row h; 21 contiguous reads each (coalesced 42B runs)
    if (tid < 240) {
        const unsigned short* sq = qt + base + tid * 21;
        const unsigned short* sv = v1 + base + tid * 21;
        unsigned short* dq = &Q[tid * 40];
        #pragma unroll
        for (int c = 0; c < 21; c++) {
            dq[c]             = sq[c];
            Vt[c * 264 + tid] = sv[c];
        }
    }
    __syncthreads();
    axial_core(Q, Vt, Pl, ybB, (size_t)b * 1209600 + w * 21);
}

// -------- K4 (MFMA): conv_out. M=64 out-ch, N=256 px, K=64 --------
__global__ __launch_bounds__(256) void k_outM(const unsigned short* __restrict__ ybA,
                                              const unsigned short* __restrict__ ybB,
                                              const float* __restrict__ w_out,
                                              const float* __restrict__ b_out,
                                              float* __restrict__ out) {
    __shared__ __align__(16) unsigned short Yl[256][72];
    __shared__ __align__(16) unsigned short Wo[64][72];
    __shared__ float bl[64];
    int tid = threadIdx.x;
    int pg = blockIdx.x * 256 + tid;

    for (int i = tid; i < 64 * 36; i += 256) ((unsigned int*)Wo)[i] = 0;
    __syncthreads();
    {
        const unsigned int* a32 = (const unsigned int*)(ybA + (size_t)pg * 42);
        unsigned short* yr = Yl[tid];
        #pragma unroll
        for (int c = 0; c < 21; c++) *(unsigned int*)&yr[c * 2] = a32[c];
        const unsigned short* bb2 = ybB + (size_t)pg * 21;
        #pragma unroll
        for (int c = 0; c < 21; c++) yr[42 + c] = bb2[c];
        #pragma unroll
        for (int c = 63; c < 72; c++) yr[c] = 0;
    }
    for (int idx = tid; idx < 3969; idx += 256) {
        int o = idx / 63, c = idx - o * 63;
        Wo[o][c] = f2b(w_out[idx]);
    }
    if (tid < 64) bl[tid] = (tid < 63) ? b_out[tid] : 0.f;
    __syncthreads();

    int wv = tid >> 6, l = tid & 63;
    int lr = l & 15, lq = l >> 4;
    const f32x4 zf = {0.f, 0.f, 0.f, 0.f};
    bf16x8 wa[4][2];
    #pragma unroll
    for (int ot = 0; ot < 4; ot++)
        #pragma unroll
        for (int ks = 0; ks < 2; ks++)
            wa[ot][ks] = *(const bf16x8*)&Wo[ot * 16 + lr][ks * 32 + lq * 8];

    int p0 = blockIdx.x * 256;
    int b = p0 / HWSZ;
    int hwb = p0 - b * HWSZ;
    for (int pt = 0; pt < 4; pt++) {
        int prow = (wv * 4 + pt) * 16;
        bf16x8 y0 = *(const bf16x8*)&Yl[prow + lr][lq * 8];
        bf16x8 y1 = *(const bf16x8*)&Yl[prow + lr][32 + lq * 8];
        f32x4 acc[4];
        #pragma unroll
        for (int ot = 0; ot < 4; ot++) {
            acc[ot] = __builtin_amdgcn_mfma_f32_16x16x32_bf16(wa[ot][0], y0, zf, 0, 0, 0);
            acc[ot] = __builtin_amdgcn_mfma_f32_16x16x32_bf16(wa[ot][1], y1, acc[ot], 0, 0, 0);
        }
        int hw = hwb + prow + lr;
        #pragma unroll
        for (int ot = 0; ot < 4; ot++) {
            #pragma unroll
            for (int r = 0; r < 4; r++) {
                int o = ot * 16 + lq * 4 + r;
                if (o < 63)
                    out[((size_t)(b * 63 + o)) * HWSZ + hw] = acc[ot][r] + bl[o];
            }
        }
    }
}

extern "C" void kernel_launch(void* const* d_in, const int* in_sizes, int n_in,
                              void* d_out, int out_size, void* d_ws, size_t ws_size,
                              hipStream_t stream) {
    const float* x     = (const float*)d_in[0];
    const float* w_in  = (const float*)d_in[1];
    const float* b_in  = (const float*)d_in[2];
    const float* gamma = (const float*)d_in[3];
    const float* beta  = (const float*)d_in[4];
    const float* mean  = (const float*)d_in[5];
    const float* var   = (const float*)d_in[6];
    const float* w_out = (const float*)d_in[7];
    const float* b_out = (const float*)d_in[8];
    float* out = (float*)d_out;

    char* ws = (char*)d_ws;
    unsigned short* xp  = (unsigned short*)ws;                 // bf16 pair-interleaved [63pair][NPIX][2]
    unsigned short* ybA = (unsigned short*)(ws + 116121600);   // bf16 [NPIX][42]
    unsigned short* Wp  = (unsigned short*)(ws + 154828800);   // bf16 [128][66] (legacy)
    float*          bp  = (float*)(ws + 154845696);            // f32 [128]
    unsigned short* Wp2 = (unsigned short*)(ws + 154846208);   // bf16 [128][64] stride-64
    unsigned short* qt  = (unsigned short*)ws;                 // alias xp pairs (dead after k_winM)
    unsigned short* v1  = (unsigned short*)(ws + 19353600);
    unsigned short* ybB = (unsigned short*)(ws + 38707200);

    k_prep <<<34, 256, 0, stream>>>(w_in, b_in, gamma, beta, mean, var, Wp, bp, Wp2);
    k_projM<<<1800, 256, 0, stream>>>(x, Wp2, bp, xp);
    k_winM <<<9216, 256, 0, stream>>>(xp, ybA);
    k_ax1  <<<1920, 256, 0, stream>>>(xp, qt, v1);
    k_ax2  <<<1920, 256, 0, stream>>>(qt, v1, ybB);
    k_outM <<<1800, 256, 0, stream>>>(ybA, ybB, w_out, b_out, out);
}

// Round 19
// 257.684 us; speedup vs baseline: 1.0651x; 1.0208x over previous
//
#include <hip/hip_runtime.h>
#include <math.h>

#define HWSZ  57600
#define NPIX  460800   // 8*57600

typedef __attribute__((ext_vector_type(8))) short bf16x8;
typedef __attribute__((ext_vector_type(4))) float f32x4;
typedef __attribute__((ext_vector_type(16))) float f32x16;
typedef __attribute__((ext_vector_type(4))) unsigned int u32x4;

__device__ __forceinline__ unsigned short f2b(float f) {
    unsigned int u = __float_as_uint(f);
    unsigned int r = (u + 0x7FFFu + ((u >> 16) & 1u)) >> 16;
    return (unsigned short)r;
}
__device__ __forceinline__ float b2f(unsigned short s) {
    return __uint_as_float(((unsigned int)s) << 16);
}

// xp layout (pair-interleaved): element(c, px) = (c & ~1)*NPIX + px*2 + (c & 1)
// dword view: dword(pair, px) = pair*NPIX + px  (pair = c>>1)

// -------- K0: fold BN into conv_in weights --------
__global__ void k_prep(const float* __restrict__ w_in, const float* __restrict__ b_in,
                       const float* __restrict__ gamma, const float* __restrict__ beta,
                       const float* __restrict__ mean,  const float* __restrict__ var,
                       unsigned short* __restrict__ Wp, float* __restrict__ bp,
                       unsigned short* __restrict__ Wp2) {
    int idx = blockIdx.x * 256 + threadIdx.x;
    if (idx < 8192) {                 // 128*64 : stride-64 packed
        int o = idx >> 6, c = idx & 63;
        unsigned short v = 0;
        if (o < 126 && c < 63) {
            float s = gamma[o] * rsqrtf(var[o] + 1e-5f);
            v = f2b(w_in[o * 63 + c] * s);
        }
        Wp2[idx] = v;
    } else if (idx < 8320) {
        int o = idx - 8192;
        float bv = 0.f;
        if (o < 126) {
            float s = gamma[o] * rsqrtf(var[o] + 1e-5f);
            bv = b_in[o] * s + beta[o] - mean[o] * s;
        }
        bp[o] = bv;
    }
}

// -------- K_proj (MFMA, round-16 measured-best: staged Xl, barrier-free, paired stores) --------
#define XS 66
__global__ __launch_bounds__(256) void k_projM(const float* __restrict__ x,
                                               const unsigned short* __restrict__ Wp2,
                                               const float* __restrict__ bp,
                                               unsigned short* __restrict__ xp) {
    __shared__ __align__(16) unsigned short Xl[256 * XS];   // [pixel][k] bf16, k=63 zero
    int blk = blockIdx.x;
    int tid = threadIdx.x;
    int b = blk / 225;
    int hw0 = (blk - b * 225) * 256;
    int wv = tid >> 6, l = tid & 63;
    int lr = l & 15, lq = l >> 4;

    // stage own pixel (wave-local LDS quarter)
    {
        const float* xb = x + (size_t)b * 63 * HWSZ + hw0 + tid;
        unsigned short* xr = &Xl[tid * XS];
        #pragma unroll
        for (int c = 0; c < 62; c += 2) {
            unsigned int lo = f2b(xb[(size_t)c * HWSZ]);
            unsigned int hi = f2b(xb[(size_t)(c + 1) * HWSZ]);
            *(unsigned int*)&xr[c] = lo | (hi << 16);
        }
        unsigned int lo = f2b(xb[(size_t)62 * HWSZ]);
        *(unsigned int*)&xr[62] = lo;   // k=63 zeroed
    }

    // W-frags direct from global (stride-64 rows, 16B aligned; L1-hot across blocks)
    bf16x8 wa[8][2];
    #pragma unroll
    for (int ot = 0; ot < 8; ot++)
        #pragma unroll
        for (int ks = 0; ks < 2; ks++)
            wa[ot][ks] = *(const bf16x8*)&Wp2[(ot * 16 + lr) * 64 + ks * 32 + lq * 8];
    f32x4 bias[8];
    #pragma unroll
    for (int ot = 0; ot < 8; ot++)
        bias[ot] = *(const f32x4*)&bp[ot * 16 + lq * 4];

    for (int pt = 0; pt < 4; pt++) {
        int prow = (wv * 4 + pt) * 16;
        bf16x8 xb0 = *(const bf16x8*)&Xl[(prow + lr) * XS + lq * 8];
        bf16x8 xb1 = *(const bf16x8*)&Xl[(prow + lr) * XS + 32 + lq * 8];
        f32x4 acc[8];
        #pragma unroll
        for (int ot = 0; ot < 8; ot++) {
            acc[ot] = __builtin_amdgcn_mfma_f32_16x16x32_bf16(wa[ot][0], xb0, bias[ot], 0, 0, 0);
            acc[ot] = __builtin_amdgcn_mfma_f32_16x16x32_bf16(wa[ot][1], xb1, acc[ot], 0, 0, 0);
        }
        size_t px = (size_t)b * HWSZ + hw0 + prow + lr;
        #pragma unroll
        for (int ot = 0; ot < 8; ot++) {
            #pragma unroll
            for (int rp = 0; rp < 2; rp++) {
                int o = ot * 16 + lq * 4 + rp * 2;   // even
                if (o < 126) {
                    unsigned int pk = (unsigned int)f2b(acc[ot][rp * 2]) |
                                      ((unsigned int)f2b(acc[ot][rp * 2 + 1]) << 16);
                    *(unsigned int*)&xp[(size_t)o * NPIX + px * 2] = pk;
                }
            }
        }
    }
}

// -------- K1 (MFMA): window attention; XCD-swizzled, dword staging, MFMA-denominator --------
// grid = 9216 (9216 % 8 == 0: bijective swizzle)
__global__ __launch_bounds__(256) void k_winM(const unsigned short* __restrict__ xp,
                                              unsigned short* __restrict__ ybA) {
    __shared__ __align__(16) unsigned short QP[4][32][40];   // Q then P' (unnormalized)
    __shared__ __align__(16) unsigned short Vtl[4][32][40];  // [ch][tok]; ch 21 = ones (tok<25)
    int bid0 = blockIdx.x;
    int bid = (bid0 & 7) * 1152 + (bid0 >> 3);
    int branch = bid / 4608;
    int r = bid - branch * 4608;
    int b = r / 576;
    int r2 = r - b * 576;
    int wi = r2 / 12;
    int g = r2 - wi * 12;
    int tid = threadIdx.x;
    int wv = tid >> 6, l = tid & 63;
    int ish = branch ? 3 : 0;
    int osh = branch ? 2 : 0;

    for (int i = tid; i < 2560; i += 256) ((unsigned int*)QP)[i] = 0;
    for (int i = tid; i < 2560; i += 256) ((unsigned int*)Vtl)[i] = 0;
    __syncthreads();

    // staging: thread -> FIXED pixel; one DWORD per channel pair (both channels)
    size_t xbase = (size_t)b * HWSZ;
    if (tid < 100) {
        int px = tid;
        int pr = px / 20, pc20 = px - pr * 20;
        int w = pc20 / 5, tok = pr * 5 + (pc20 - w * 5);
        int ih = wi * 5 + pr + ish; if (ih >= 240) ih -= 240;
        int iw = g * 20 + pc20 + ish; if (iw >= 240) iw -= 240;
        size_t pix = xbase + ih * 240 + iw;
        const unsigned int* src32 = (const unsigned int*)xp + (size_t)(branch * 21) * NPIX + pix;
        unsigned short* dq = &QP[w][tok][0];
        #pragma unroll
        for (int cc = 0; cc < 21; cc++) {
            unsigned int d = src32[(size_t)cc * NPIX];
            unsigned short lo = (unsigned short)d, hi = (unsigned short)(d >> 16);
            const int c0 = 2 * cc, c1 = 2 * cc + 1;
            if (c0 < 21) dq[c0] = lo; else Vtl[w][c0 - 21][tok] = lo;
            if (c1 < 21) dq[c1] = hi; else Vtl[w][c1 - 21][tok] = hi;
        }
    }
    if (tid < 100) {   // ones row (denominator channel), valid tokens only
        int w = tid / 25, tok = tid - (tid / 25) * 25;
        Vtl[w][21][tok] = 0x3F80;
    }
    __syncthreads();

    int lr32 = l & 31, hi = l >> 5;
    f32x16 z16;
    #pragma unroll
    for (int i = 0; i < 16; i++) z16[i] = 0.f;

    // S = Q Q^T
    bf16x8 a0 = *(const bf16x8*)&QP[wv][lr32][hi * 8];
    bf16x8 a1 = *(const bf16x8*)&QP[wv][lr32][16 + hi * 8];
    f32x16 S = __builtin_amdgcn_mfma_f32_32x32x16_bf16(a0, a0, z16, 0, 0, 0);
    S = __builtin_amdgcn_mfma_f32_32x32x16_bf16(a1, a1, S, 0, 0, 0);

    // P' = exp(S) unnormalized -> LDS (overwrite own Q stripe).
    // |S| <= ~30 << 88 so no max-subtraction needed; pad cols exp(0)=1 x zero V.
    #pragma unroll
    for (int rg = 0; rg < 16; rg++) {
        float e = __expf(S[rg]);
        int row = (rg & 3) + 8 * (rg >> 2) + 4 * hi;
        QP[wv][row][lr32] = f2b(e);
    }

    // Y = P' V ; col 21 = row-sum (denominator)
    bf16x8 pa0 = *(const bf16x8*)&QP[wv][lr32][hi * 8];
    bf16x8 pa1 = *(const bf16x8*)&QP[wv][lr32][16 + hi * 8];
    bf16x8 vb0 = *(const bf16x8*)&Vtl[wv][lr32][hi * 8];
    bf16x8 vb1 = *(const bf16x8*)&Vtl[wv][lr32][16 + hi * 8];
    f32x16 Y = __builtin_amdgcn_mfma_f32_32x32x16_bf16(pa0, vb0, z16, 0, 0, 0);
    Y = __builtin_amdgcn_mfma_f32_32x32x16_bf16(pa1, vb1, Y, 0, 0, 0);

    size_t obb = (size_t)b * HWSZ;
    int wi5 = wi * 5 + osh, g20 = g * 20 + wv * 5 + osh;
    #pragma unroll
    for (int rg = 0; rg < 16; rg++) {
        int tok = (rg & 3) + 8 * (rg >> 2) + 4 * hi;
        if (tok < 25) {
            float den = __shfl(Y[rg], 21, 32);
            float v = Y[rg] * (1.0f / den);
            int pr = tok / 5, pc = tok - (tok / 5) * 5;
            int oh = wi5 + pr; if (oh >= 240) oh -= 240;
            int ow = g20 + pc; if (ow >= 240) ow -= 240;
            if (lr32 < 21)
                ybA[(obb + oh * 240 + ow) * 42 + branch * 21 + lr32] = f2b(v);
        }
    }
}

// -------- MFMA axial attention core (verified round 4) --------
__device__ __forceinline__ void axial_core(const unsigned short* Q, const unsigned short* Vt,
                                           unsigned short* Pl,
                                           unsigned short* outp, size_t obase) {
    int tid = threadIdx.x;
    int wv = tid >> 6, l = tid & 63;
    int lr = l & 15, lq = l >> 4;
    const f32x4 zf = {0.f, 0.f, 0.f, 0.f};
    int m0 = wv * 16;

    for (int mt = 0; mt < 4; mt++) {
        if (mt == 3 && wv == 3) continue;   // tile 15 would be rows 240..255 (OOB)
        int rbase = mt * 64 + wv * 16;
        bf16x8 afr = *(const bf16x8*)&Q[(rbase + lr) * 40 + lq * 8];
        f32x4 d[15];
        #pragma unroll
        for (int jt = 0; jt < 15; jt++) {
            bf16x8 bfr = *(const bf16x8*)&Q[(jt * 16 + lr) * 40 + lq * 8];
            d[jt] = __builtin_amdgcn_mfma_f32_16x16x32_bf16(afr, bfr, zf, 0, 0, 0);
        }
        float mx[4] = {-1e30f, -1e30f, -1e30f, -1e30f};
        #pragma unroll
        for (int jt = 0; jt < 15; jt++)
            #pragma unroll
            for (int r = 0; r < 4; r++) mx[r] = fmaxf(mx[r], d[jt][r]);
        #pragma unroll
        for (int s = 1; s < 16; s <<= 1)
            #pragma unroll
            for (int r = 0; r < 4; r++) mx[r] = fmaxf(mx[r], __shfl_xor(mx[r], s));
        float sm[4] = {0.f, 0.f, 0.f, 0.f};
        #pragma unroll
        for (int jt = 0; jt < 15; jt++)
            #pragma unroll
            for (int r = 0; r < 4; r++) { float e = __expf(d[jt][r] - mx[r]); d[jt][r] = e; sm[r] += e; }
        #pragma unroll
        for (int s = 1; s < 16; s <<= 1)
            #pragma unroll
            for (int r = 0; r < 4; r++) sm[r] += __shfl_xor(sm[r], s);
        float inv[4];
        #pragma unroll
        for (int r = 0; r < 4; r++) inv[r] = 1.0f / sm[r];

        #pragma unroll
        for (int jt = 0; jt < 8; jt++)
            #pragma unroll
            for (int r = 0; r < 4; r++)
                Pl[(m0 + lq * 4 + r) * 136 + jt * 16 + lr] = f2b(d[jt][r] * inv[r]);
        f32x4 y0 = zf, y1 = zf;
        #pragma unroll
        for (int ks = 0; ks < 4; ks++) {
            bf16x8 pa = *(const bf16x8*)&Pl[(m0 + lr) * 136 + ks * 32 + lq * 8];
            bf16x8 v0 = *(const bf16x8*)&Vt[lr * 264 + ks * 32 + lq * 8];
            bf16x8 v1f = *(const bf16x8*)&Vt[(lr + 16) * 264 + ks * 32 + lq * 8];
            y0 = __builtin_amdgcn_mfma_f32_16x16x32_bf16(pa, v0, y0, 0, 0, 0);
            y1 = __builtin_amdgcn_mfma_f32_16x16x32_bf16(pa, v1f, y1, 0, 0, 0);
        }
        #pragma unroll
        for (int jt = 8; jt < 15; jt++)
            #pragma unroll
            for (int r = 0; r < 4; r++)
                Pl[(m0 + lq * 4 + r) * 136 + (jt - 8) * 16 + lr] = f2b(d[jt][r] * inv[r]);
        #pragma unroll
        for (int r = 0; r < 4; r++)
            Pl[(m0 + lq * 4 + r) * 136 + 112 + lr] = 0;
        #pragma unroll
        for (int ks = 0; ks < 4; ks++) {
            bf16x8 pa = *(const bf16x8*)&Pl[(m0 + lr) * 136 + ks * 32 + lq * 8];
            bf16x8 v0 = *(const bf16x8*)&Vt[lr * 264 + (ks + 4) * 32 + lq * 8];
            bf16x8 v1f = *(const bf16x8*)&Vt[(lr + 16) * 264 + (ks + 4) * 32 + lq * 8];
            y0 = __builtin_amdgcn_mfma_f32_16x16x32_bf16(pa, v0, y0, 0, 0, 0);
            y1 = __builtin_amdgcn_mfma_f32_16x16x32_bf16(pa, v1f, y1, 0, 0, 0);
        }
        #pragma unroll
        for (int r = 0; r < 4; r++) {
            int tok = rbase + lq * 4 + r;
            size_t oa = obase + (size_t)tok * 5040;
            outp[oa + lr] = f2b(y0[r]);
            if (lr < 5) outp[oa + 16 + lr] = f2b(y1[r]);
        }
    }
}

// -------- K2: axial stage 1 (tokens along w). grid = 1920 --------
__global__ __launch_bounds__(256) void k_ax1(const unsigned short* __restrict__ xp,
                                             unsigned short* __restrict__ qt,
                                             unsigned short* __restrict__ v1) {
    __shared__ __align__(16) unsigned short Q[240 * 40];
    __shared__ __align__(16) unsigned short Vt[32 * 264];
    __shared__ __align__(16) unsigned short Pl[64 * 136];
    int b = blockIdx.x / 240, h = blockIdx.x % 240;
    int tid = threadIdx.x;
    for (int i = tid; i < 4800; i += 256) ((unsigned int*)Q)[i] = 0;
    for (int i = tid; i < 4224; i += 256) ((unsigned int*)Vt)[i] = 0;
    __syncthreads();
    size_t xb = (size_t)b * HWSZ + h * 240;
    // staging: thread -> fixed w; one DWORD per channel pair (pairs 42..62 = ch 84..125)
    if (tid < 240) {
        const unsigned int* src32 = (const unsigned int*)xp + (size_t)42 * NPIX + xb + tid;
        unsigned short* dq = &Q[tid * 40];
        #pragma unroll
        for (int cc = 0; cc < 21; cc++) {
            unsigned int d = src32[(size_t)cc * NPIX];
            unsigned short lo = (unsigned short)d, hi = (unsigned short)(d >> 16);
            const int c0 = 2 * cc, c1 = 2 * cc + 1;   // relative to ch 84
            if (c0 < 21) dq[c0] = lo; else Vt[(c0 - 21) * 264 + tid] = lo;
            if (c1 < 21) dq[c1] = hi; else Vt[(c1 - 21) * 264 + tid] = hi;
        }
    }
    __syncthreads();
    size_t qtb = (size_t)b * 1209600 + h * 21;
    for (int idx = tid; idx < 5040; idx += 256) {
        int w = idx / 21, c = idx - w * 21;
        qt[qtb + (size_t)w * 5040 + c] = Q[w * 40 + c];
    }
    axial_core(Q, Vt, Pl, v1, (size_t)b * 1209600 + h * 21);
}

// -------- K3: axial stage 2 (tokens along h). grid = 1920 --------
__global__ __launch_bounds__(256) void k_ax2(const unsigned short* __restrict__ qt,
                                             const unsigned short* __restrict__ v1,
                                             unsigned short* __restrict__ ybB) {
    __shared__ __align__(16) unsigned short Q[240 * 40];
    __shared__ __align__(16) unsigned short Vt[32 * 264];
    __shared__ __align__(16) unsigned short Pl[64 * 136];
    int b = blockIdx.x / 240, w = blockIdx.x % 240;
    int tid = threadIdx.x;
    for (int i = tid; i < 4800; i += 256) ((unsigned int*)Q)[i] = 0;
    for (int i = tid; i < 4224; i += 256) ((unsigned int*)Vt)[i] = 0;
    __syncthreads();
    size_t base = ((size_t)b * 240 + w) * 5040;
    // staging: thread -> fixed token row h; 21 contiguous reads each (coalesced 42B runs)
    if (tid < 240) {
        const unsigned short* sq = qt + base + tid * 21;
        const unsigned short* sv = v1 + base + tid * 21;
        unsigned short* dq = &Q[tid * 40];
        #pragma unroll
        for (int c = 0; c < 21; c++) {
            dq[c]             = sq[c];
            Vt[c * 264 + tid] = sv[c];
        }
    }
    __syncthreads();
    axial_core(Q, Vt, Pl, ybB, (size_t)b * 1209600 + w * 21);
}

// -------- K4 (MFMA): conv_out. M=64 out-ch, N=256 px, K=64 --------
__global__ __launch_bounds__(256) void k_outM(const unsigned short* __restrict__ ybA,
                                              const unsigned short* __restrict__ ybB,
                                              const float* __restrict__ w_out,
                                              const float* __restrict__ b_out,
                                              float* __restrict__ out) {
    __shared__ __align__(16) unsigned short Yl[256][72];
    __shared__ __align__(16) unsigned short Wo[64][72];
    __shared__ float bl[64];
    int tid = threadIdx.x;
    int pg = blockIdx.x * 256 + tid;

    for (int i = tid; i < 64 * 36; i += 256) ((unsigned int*)Wo)[i] = 0;
    __syncthreads();
    {
        const unsigned int* a32 = (const unsigned int*)(ybA + (size_t)pg * 42);
        unsigned short* yr = Yl[tid];
        #pragma unroll
        for (int c = 0; c < 21; c++) *(unsigned int*)&yr[c * 2] = a32[c];
        const unsigned short* bb2 = ybB + (size_t)pg * 21;
        #pragma unroll
        for (int c = 0; c < 21; c++) yr[42 + c] = bb2[c];
        #pragma unroll
        for (int c = 63; c < 72; c++) yr[c] = 0;
    }
    for (int idx = tid; idx < 3969; idx += 256) {
        int o = idx / 63, c = idx - o * 63;
        Wo[o][c] = f2b(w_out[idx]);
    }
    if (tid < 64) bl[tid] = (tid < 63) ? b_out[tid] : 0.f;
    __syncthreads();

    int wv = tid >> 6, l = tid & 63;
    int lr = l & 15, lq = l >> 4;
    const f32x4 zf = {0.f, 0.f, 0.f, 0.f};
    bf16x8 wa[4][2];
    #pragma unroll
    for (int ot = 0; ot < 4; ot++)
        #pragma unroll
        for (int ks = 0; ks < 2; ks++)
            wa[ot][ks] = *(const bf16x8*)&Wo[ot * 16 + lr][ks * 32 + lq * 8];

    int p0 = blockIdx.x * 256;
    int b = p0 / HWSZ;
    int hwb = p0 - b * HWSZ;
    for (int pt = 0; pt < 4; pt++) {
        int prow = (wv * 4 + pt) * 16;
        bf16x8 y0 = *(const bf16x8*)&Yl[prow + lr][lq * 8];
        bf16x8 y1 = *(const bf16x8*)&Yl[prow + lr][32 + lq * 8];
        f32x4 acc[4];
        #pragma unroll
        for (int ot = 0; ot < 4; ot++) {
            acc[ot] = __builtin_amdgcn_mfma_f32_16x16x32_bf16(wa[ot][0], y0, zf, 0, 0, 0);
            acc[ot] = __builtin_amdgcn_mfma_f32_16x16x32_bf16(wa[ot][1], y1, acc[ot], 0, 0, 0);
        }
        int hw = hwb + prow + lr;
        #pragma unroll
        for (int ot = 0; ot < 4; ot++) {
            #pragma unroll
            for (int r = 0; r < 4; r++) {
                int o = ot * 16 + lq * 4 + r;
                if (o < 63)
                    out[((size_t)(b * 63 + o)) * HWSZ + hw] = acc[ot][r] + bl[o];
            }
        }
    }
}

extern "C" void kernel_launch(void* const* d_in, const int* in_sizes, int n_in,
                              void* d_out, int out_size, void* d_ws, size_t ws_size,
                              hipStream_t stream) {
    const float* x     = (const float*)d_in[0];
    const float* w_in  = (const float*)d_in[1];
    const float* b_in  = (const float*)d_in[2];
    const float* gamma = (const float*)d_in[3];
    const float* beta  = (const float*)d_in[4];
    const float* mean  = (const float*)d_in[5];
    const float* var   = (const float*)d_in[6];
    const float* w_out = (const float*)d_in[7];
    const float* b_out = (const float*)d_in[8];
    float* out = (float*)d_out;

    char* ws = (char*)d_ws;
    unsigned short* xp  = (unsigned short*)ws;                 // bf16 pair-interleaved [63pair][NPIX][2]
    unsigned short* ybA = (unsigned short*)(ws + 116121600);   // bf16 [NPIX][42]
    unsigned short* Wp  = (unsigned short*)(ws + 154828800);   // bf16 [128][66] (legacy)
    float*          bp  = (float*)(ws + 154845696);            // f32 [128]
    unsigned short* Wp2 = (unsigned short*)(ws + 154846208);   // bf16 [128][64] stride-64
    unsigned short* qt  = (unsigned short*)ws;                 // alias xp pairs (dead after k_winM)
    unsigned short* v1  = (unsigned short*)(ws + 19353600);
    unsigned short* ybB = (unsigned short*)(ws + 38707200);

    k_prep <<<34, 256, 0, stream>>>(w_in, b_in, gamma, beta, mean, var, Wp, bp, Wp2);
    k_projM<<<1800, 256, 0, stream>>>(x, Wp2, bp, xp);
    k_winM <<<9216, 256, 0, stream>>>(xp, ybA);
    k_ax1  <<<1920, 256, 0, stream>>>(xp, qt, v1);
    k_ax2  <<<1920, 256, 0, stream>>>(qt, v1, ybB);
    k_outM <<<1800, 256, 0, stream>>>(ybA, ybB, w_out, b_out, out);
}

// Round 20
// 257.554 us; speedup vs baseline: 1.0657x; 1.0005x over previous
//
#include <hip/hip_runtime.h>
#include <math.h>

#define HWSZ  57600
#define NPIX  460800   // 8*57600

typedef __attribute__((ext_vector_type(8))) short bf16x8;
typedef __attribute__((ext_vector_type(4))) float f32x4;
typedef __attribute__((ext_vector_type(16))) float f32x16;
typedef __attribute__((ext_vector_type(4))) unsigned int u32x4;

__device__ __forceinline__ unsigned short f2b(float f) {
    unsigned int u = __float_as_uint(f);
    unsigned int r = (u + 0x7FFFu + ((u >> 16) & 1u)) >> 16;
    return (unsigned short)r;
}
__device__ __forceinline__ float b2f(unsigned short s) {
    return __uint_as_float(((unsigned int)s) << 16);
}

// xp layout (pair-interleaved): element(c, px) = (c & ~1)*NPIX + px*2 + (c & 1)
// dword view: dword(pair, px) = pair*NPIX + px  (pair = c>>1)

// -------- K0: fold BN into conv_in weights; pre-pack conv_out weights --------
__global__ void k_prep(const float* __restrict__ w_in, const float* __restrict__ b_in,
                       const float* __restrict__ gamma, const float* __restrict__ beta,
                       const float* __restrict__ mean,  const float* __restrict__ var,
                       const float* __restrict__ w_out,
                       float* __restrict__ bp, unsigned short* __restrict__ Wp2,
                       unsigned short* __restrict__ Wo2) {
    int idx = blockIdx.x * 256 + threadIdx.x;
    if (idx < 8192) {                 // Wp2: 128*64 stride-64 packed (BN folded)
        int o = idx >> 6, c = idx & 63;
        unsigned short v = 0;
        if (o < 126 && c < 63) {
            float s = gamma[o] * rsqrtf(var[o] + 1e-5f);
            v = f2b(w_in[o * 63 + c] * s);
        }
        Wp2[idx] = v;
    } else if (idx < 8320) {
        int o = idx - 8192;
        float bv = 0.f;
        if (o < 126) {
            float s = gamma[o] * rsqrtf(var[o] + 1e-5f);
            bv = b_in[o] * s + beta[o] - mean[o] * s;
        }
        bp[o] = bv;
    } else if (idx < 12416) {         // Wo2: 64*64 stride-64 packed
        int j = idx - 8320;
        int o = j >> 6, c = j & 63;
        unsigned short v = 0;
        if (o < 63 && c < 63) v = f2b(w_out[o * 63 + c]);
        Wo2[j] = v;
    }
}

// -------- K_proj (MFMA, measured-best: staged Xl, barrier-free, paired stores) --------
#define XS 66
__global__ __launch_bounds__(256) void k_projM(const float* __restrict__ x,
                                               const unsigned short* __restrict__ Wp2,
                                               const float* __restrict__ bp,
                                               unsigned short* __restrict__ xp) {
    __shared__ __align__(16) unsigned short Xl[256 * XS];   // [pixel][k] bf16, k=63 zero
    int blk = blockIdx.x;
    int tid = threadIdx.x;
    int b = blk / 225;
    int hw0 = (blk - b * 225) * 256;
    int wv = tid >> 6, l = tid & 63;
    int lr = l & 15, lq = l >> 4;

    // stage own pixel (wave-local LDS quarter)
    {
        const float* xb = x + (size_t)b * 63 * HWSZ + hw0 + tid;
        unsigned short* xr = &Xl[tid * XS];
        #pragma unroll
        for (int c = 0; c < 62; c += 2) {
            unsigned int lo = f2b(xb[(size_t)c * HWSZ]);
            unsigned int hi = f2b(xb[(size_t)(c + 1) * HWSZ]);
            *(unsigned int*)&xr[c] = lo | (hi << 16);
        }
        unsigned int lo = f2b(xb[(size_t)62 * HWSZ]);
        *(unsigned int*)&xr[62] = lo;   // k=63 zeroed
    }

    // W-frags direct from global (stride-64 rows, 16B aligned; L1-hot across blocks)
    bf16x8 wa[8][2];
    #pragma unroll
    for (int ot = 0; ot < 8; ot++)
        #pragma unroll
        for (int ks = 0; ks < 2; ks++)
            wa[ot][ks] = *(const bf16x8*)&Wp2[(ot * 16 + lr) * 64 + ks * 32 + lq * 8];
    f32x4 bias[8];
    #pragma unroll
    for (int ot = 0; ot < 8; ot++)
        bias[ot] = *(const f32x4*)&bp[ot * 16 + lq * 4];

    for (int pt = 0; pt < 4; pt++) {
        int prow = (wv * 4 + pt) * 16;
        bf16x8 xb0 = *(const bf16x8*)&Xl[(prow + lr) * XS + lq * 8];
        bf16x8 xb1 = *(const bf16x8*)&Xl[(prow + lr) * XS + 32 + lq * 8];
        f32x4 acc[8];
        #pragma unroll
        for (int ot = 0; ot < 8; ot++) {
            acc[ot] = __builtin_amdgcn_mfma_f32_16x16x32_bf16(wa[ot][0], xb0, bias[ot], 0, 0, 0);
            acc[ot] = __builtin_amdgcn_mfma_f32_16x16x32_bf16(wa[ot][1], xb1, acc[ot], 0, 0, 0);
        }
        size_t px = (size_t)b * HWSZ + hw0 + prow + lr;
        #pragma unroll
        for (int ot = 0; ot < 8; ot++) {
            #pragma unroll
            for (int rp = 0; rp < 2; rp++) {
                int o = ot * 16 + lq * 4 + rp * 2;   // even
                if (o < 126) {
                    unsigned int pk = (unsigned int)f2b(acc[ot][rp * 2]) |
                                      ((unsigned int)f2b(acc[ot][rp * 2 + 1]) << 16);
                    *(unsigned int*)&xp[(size_t)o * NPIX + px * 2] = pk;
                }
            }
        }
    }
}

// -------- K1 (MFMA): window attention; XCD-swizzled, dword staging, MFMA-denominator --------
// grid = 9216 (9216 % 8 == 0: bijective swizzle)
__global__ __launch_bounds__(256) void k_winM(const unsigned short* __restrict__ xp,
                                              unsigned short* __restrict__ ybA) {
    __shared__ __align__(16) unsigned short QP[4][32][40];   // Q then P' (unnormalized)
    __shared__ __align__(16) unsigned short Vtl[4][32][40];  // [ch][tok]; ch 21 = ones (tok<25)
    int bid0 = blockIdx.x;
    int bid = (bid0 & 7) * 1152 + (bid0 >> 3);
    int branch = bid / 4608;
    int r = bid - branch * 4608;
    int b = r / 576;
    int r2 = r - b * 576;
    int wi = r2 / 12;
    int g = r2 - wi * 12;
    int tid = threadIdx.x;
    int wv = tid >> 6, l = tid & 63;
    int ish = branch ? 3 : 0;
    int osh = branch ? 2 : 0;

    for (int i = tid; i < 2560; i += 256) ((unsigned int*)QP)[i] = 0;
    for (int i = tid; i < 2560; i += 256) ((unsigned int*)Vtl)[i] = 0;
    __syncthreads();

    // staging: thread -> FIXED pixel; one DWORD per channel pair (both channels)
    size_t xbase = (size_t)b * HWSZ;
    if (tid < 100) {
        int px = tid;
        int pr = px / 20, pc20 = px - pr * 20;
        int w = pc20 / 5, tok = pr * 5 + (pc20 - w * 5);
        int ih = wi * 5 + pr + ish; if (ih >= 240) ih -= 240;
        int iw = g * 20 + pc20 + ish; if (iw >= 240) iw -= 240;
        size_t pix = xbase + ih * 240 + iw;
        const unsigned int* src32 = (const unsigned int*)xp + (size_t)(branch * 21) * NPIX + pix;
        unsigned short* dq = &QP[w][tok][0];
        #pragma unroll
        for (int cc = 0; cc < 21; cc++) {
            unsigned int d = src32[(size_t)cc * NPIX];
            unsigned short lo = (unsigned short)d, hi = (unsigned short)(d >> 16);
            const int c0 = 2 * cc, c1 = 2 * cc + 1;
            if (c0 < 21) dq[c0] = lo; else Vtl[w][c0 - 21][tok] = lo;
            if (c1 < 21) dq[c1] = hi; else Vtl[w][c1 - 21][tok] = hi;
        }
    }
    if (tid < 100) {   // ones row (denominator channel), valid tokens only
        int w = tid / 25, tok = tid - (tid / 25) * 25;
        Vtl[w][21][tok] = 0x3F80;
    }
    __syncthreads();

    int lr32 = l & 31, hi = l >> 5;
    f32x16 z16;
    #pragma unroll
    for (int i = 0; i < 16; i++) z16[i] = 0.f;

    // S = Q Q^T
    bf16x8 a0 = *(const bf16x8*)&QP[wv][lr32][hi * 8];
    bf16x8 a1 = *(const bf16x8*)&QP[wv][lr32][16 + hi * 8];
    f32x16 S = __builtin_amdgcn_mfma_f32_32x32x16_bf16(a0, a0, z16, 0, 0, 0);
    S = __builtin_amdgcn_mfma_f32_32x32x16_bf16(a1, a1, S, 0, 0, 0);

    // P' = exp(S) unnormalized -> LDS (overwrite own Q stripe).
    #pragma unroll
    for (int rg = 0; rg < 16; rg++) {
        float e = __expf(S[rg]);
        int row = (rg & 3) + 8 * (rg >> 2) + 4 * hi;
        QP[wv][row][lr32] = f2b(e);
    }

    // Y = P' V ; col 21 = row-sum (denominator)
    bf16x8 pa0 = *(const bf16x8*)&QP[wv][lr32][hi * 8];
    bf16x8 pa1 = *(const bf16x8*)&QP[wv][lr32][16 + hi * 8];
    bf16x8 vb0 = *(const bf16x8*)&Vtl[wv][lr32][hi * 8];
    bf16x8 vb1 = *(const bf16x8*)&Vtl[wv][lr32][16 + hi * 8];
    f32x16 Y = __builtin_amdgcn_mfma_f32_32x32x16_bf16(pa0, vb0, z16, 0, 0, 0);
    Y = __builtin_amdgcn_mfma_f32_32x32x16_bf16(pa1, vb1, Y, 0, 0, 0);

    size_t obb = (size_t)b * HWSZ;
    int wi5 = wi * 5 + osh, g20 = g * 20 + wv * 5 + osh;
    #pragma unroll
    for (int rg = 0; rg < 16; rg++) {
        int tok = (rg & 3) + 8 * (rg >> 2) + 4 * hi;
        if (tok < 25) {
            float den = __shfl(Y[rg], 21, 32);
            float v = Y[rg] * (1.0f / den);
            int pr = tok / 5, pc = tok - (tok / 5) * 5;
            int oh = wi5 + pr; if (oh >= 240) oh -= 240;
            int ow = g20 + pc; if (ow >= 240) ow -= 240;
            if (lr32 < 21)
                ybA[(obb + oh * 240 + ow) * 42 + branch * 21 + lr32] = f2b(v);
        }
    }
}

// -------- MFMA axial attention core (verified round 4) --------
__device__ __forceinline__ void axial_core(const unsigned short* Q, const unsigned short* Vt,
                                           unsigned short* Pl,
                                           unsigned short* outp, size_t obase) {
    int tid = threadIdx.x;
    int wv = tid >> 6, l = tid & 63;
    int lr = l & 15, lq = l >> 4;
    const f32x4 zf = {0.f, 0.f, 0.f, 0.f};
    int m0 = wv * 16;

    for (int mt = 0; mt < 4; mt++) {
        if (mt == 3 && wv == 3) continue;   // tile 15 would be rows 240..255 (OOB)
        int rbase = mt * 64 + wv * 16;
        bf16x8 afr = *(const bf16x8*)&Q[(rbase + lr) * 40 + lq * 8];
        f32x4 d[15];
        #pragma unroll
        for (int jt = 0; jt < 15; jt++) {
            bf16x8 bfr = *(const bf16x8*)&Q[(jt * 16 + lr) * 40 + lq * 8];
            d[jt] = __builtin_amdgcn_mfma_f32_16x16x32_bf16(afr, bfr, zf, 0, 0, 0);
        }
        float mx[4] = {-1e30f, -1e30f, -1e30f, -1e30f};
        #pragma unroll
        for (int jt = 0; jt < 15; jt++)
            #pragma unroll
            for (int r = 0; r < 4; r++) mx[r] = fmaxf(mx[r], d[jt][r]);
        #pragma unroll
        for (int s = 1; s < 16; s <<= 1)
            #pragma unroll
            for (int r = 0; r < 4; r++) mx[r] = fmaxf(mx[r], __shfl_xor(mx[r], s));
        float sm[4] = {0.f, 0.f, 0.f, 0.f};
        #pragma unroll
        for (int jt = 0; jt < 15; jt++)
            #pragma unroll
            for (int r = 0; r < 4; r++) { float e = __expf(d[jt][r] - mx[r]); d[jt][r] = e; sm[r] += e; }
        #pragma unroll
        for (int s = 1; s < 16; s <<= 1)
            #pragma unroll
            for (int r = 0; r < 4; r++) sm[r] += __shfl_xor(sm[r], s);
        float inv[4];
        #pragma unroll
        for (int r = 0; r < 4; r++) inv[r] = 1.0f / sm[r];

        #pragma unroll
        for (int jt = 0; jt < 8; jt++)
            #pragma unroll
            for (int r = 0; r < 4; r++)
                Pl[(m0 + lq * 4 + r) * 136 + jt * 16 + lr] = f2b(d[jt][r] * inv[r]);
        f32x4 y0 = zf, y1 = zf;
        #pragma unroll
        for (int ks = 0; ks < 4; ks++) {
            bf16x8 pa = *(const bf16x8*)&Pl[(m0 + lr) * 136 + ks * 32 + lq * 8];
            bf16x8 v0 = *(const bf16x8*)&Vt[lr * 264 + ks * 32 + lq * 8];
            bf16x8 v1f = *(const bf16x8*)&Vt[(lr + 16) * 264 + ks * 32 + lq * 8];
            y0 = __builtin_amdgcn_mfma_f32_16x16x32_bf16(pa, v0, y0, 0, 0, 0);
            y1 = __builtin_amdgcn_mfma_f32_16x16x32_bf16(pa, v1f, y1, 0, 0, 0);
        }
        #pragma unroll
        for (int jt = 8; jt < 15; jt++)
            #pragma unroll
            for (int r = 0; r < 4; r++)
                Pl[(m0 + lq * 4 + r) * 136 + (jt - 8) * 16 + lr] = f2b(d[jt][r] * inv[r]);
        #pragma unroll
        for (int r = 0; r < 4; r++)
            Pl[(m0 + lq * 4 + r) * 136 + 112 + lr] = 0;
        #pragma unroll
        for (int ks = 0; ks < 4; ks++) {
            bf16x8 pa = *(const bf16x8*)&Pl[(m0 + lr) * 136 + ks * 32 + lq * 8];
            bf16x8 v0 = *(const bf16x8*)&Vt[lr * 264 + (ks + 4) * 32 + lq * 8];
            bf16x8 v1f = *(const bf16x8*)&Vt[(lr + 16) * 264 + (ks + 4) * 32 + lq * 8];
            y0 = __builtin_amdgcn_mfma_f32_16x16x32_bf16(pa, v0, y0, 0, 0, 0);
            y1 = __builtin_amdgcn_mfma_f32_16x16x32_bf16(pa, v1f, y1, 0, 0, 0);
        }
        #pragma unroll
        for (int r = 0; r < 4; r++) {
            int tok = rbase + lq * 4 + r;
            size_t oa = obase + (size_t)tok * 5040;
            outp[oa + lr] = f2b(y0[r]);
            if (lr < 5) outp[oa + 16 + lr] = f2b(y1[r]);
        }
    }
}

// -------- K2: axial stage 1 (tokens along w). grid = 1920 --------
__global__ __launch_bounds__(256) void k_ax1(const unsigned short* __restrict__ xp,
                                             unsigned short* __restrict__ qt,
                                             unsigned short* __restrict__ v1) {
    __shared__ __align__(16) unsigned short Q[240 * 40];
    __shared__ __align__(16) unsigned short Vt[32 * 264];
    __shared__ __align__(16) unsigned short Pl[64 * 136];
    int b = blockIdx.x / 240, h = blockIdx.x % 240;
    int tid = threadIdx.x;
    for (int i = tid; i < 4800; i += 256) ((unsigned int*)Q)[i] = 0;
    for (int i = tid; i < 4224; i += 256) ((unsigned int*)Vt)[i] = 0;
    __syncthreads();
    size_t xb = (size_t)b * HWSZ + h * 240;
    // staging: thread -> fixed w; one DWORD per channel pair (pairs 42..62 = ch 84..125)
    if (tid < 240) {
        const unsigned int* src32 = (const unsigned int*)xp + (size_t)42 * NPIX + xb + tid;
        unsigned short* dq = &Q[tid * 40];
        #pragma unroll
        for (int cc = 0; cc < 21; cc++) {
            unsigned int d = src32[(size_t)cc * NPIX];
            unsigned short lo = (unsigned short)d, hi = (unsigned short)(d >> 16);
            const int c0 = 2 * cc, c1 = 2 * cc + 1;   // relative to ch 84
            if (c0 < 21) dq[c0] = lo; else Vt[(c0 - 21) * 264 + tid] = lo;
            if (c1 < 21) dq[c1] = hi; else Vt[(c1 - 21) * 264 + tid] = hi;
        }
    }
    __syncthreads();
    size_t qtb = (size_t)b * 1209600 + h * 21;
    for (int idx = tid; idx < 5040; idx += 256) {
        int w = idx / 21, c = idx - w * 21;
        qt[qtb + (size_t)w * 5040 + c] = Q[w * 40 + c];
    }
    axial_core(Q, Vt, Pl, v1, (size_t)b * 1209600 + h * 21);
}

// -------- K3: axial stage 2 (tokens along h). grid = 1920 --------
__global__ __launch_bounds__(256) void k_ax2(const unsigned short* __restrict__ qt,
                                             const unsigned short* __restrict__ v1,
                                             unsigned short* __restrict__ ybB) {
    __shared__ __align__(16) unsigned short Q[240 * 40];
    __shared__ __align__(16) unsigned short Vt[32 * 264];
    __shared__ __align__(16) unsigned short Pl[64 * 136];
    int b = blockIdx.x / 240, w = blockIdx.x % 240;
    int tid = threadIdx.x;
    for (int i = tid; i < 4800; i += 256) ((unsigned int*)Q)[i] = 0;
    for (int i = tid; i < 4224; i += 256) ((unsigned int*)Vt)[i] = 0;
    __syncthreads();
    size_t base = ((size_t)b * 240 + w) * 5040;
    // staging: thread -> fixed token row h; 21 contiguous reads each (coalesced 42B runs)
    if (tid < 240) {
        const unsigned short* sq = qt + base + tid * 21;
        const unsigned short* sv = v1 + base + tid * 21;
        unsigned short* dq = &Q[tid * 40];
        #pragma unroll
        for (int c = 0; c < 21; c++) {
            dq[c]             = sq[c];
            Vt[c * 264 + tid] = sv[c];
        }
    }
    __syncthreads();
    axial_core(Q, Vt, Pl, ybB, (size_t)b * 1209600 + w * 21);
}

// -------- K4 (MFMA): conv_out, barrier-free (wave-local Yl; W-frags from global) --------
__global__ __launch_bounds__(256) void k_outM(const unsigned short* __restrict__ ybA,
                                              const unsigned short* __restrict__ ybB,
                                              const unsigned short* __restrict__ Wo2,
                                              const float* __restrict__ b_out,
                                              float* __restrict__ out) {
    __shared__ __align__(16) unsigned short Yl[256][72];
    int tid = threadIdx.x;
    int pg = blockIdx.x * 256 + tid;
    int wv = tid >> 6, l = tid & 63;
    int lr = l & 15, lq = l >> 4;

    // stage own pixel row (wave-local: wave wv reads rows [wv*64, wv*64+64) only)
    {
        const unsigned int* a32 = (const unsigned int*)(ybA + (size_t)pg * 42);
        unsigned short* yr = Yl[tid];
        #pragma unroll
        for (int c = 0; c < 21; c++) *(unsigned int*)&yr[c * 2] = a32[c];
        const unsigned short* bb2 = ybB + (size_t)pg * 21;
        #pragma unroll
        for (int c = 0; c < 21; c++) yr[42 + c] = bb2[c];
        #pragma unroll
        for (int c = 63; c < 72; c++) yr[c] = 0;
    }

    // W-frags + bias direct from global (stride-64 rows; L1-hot across blocks)
    bf16x8 wa[4][2];
    #pragma unroll
    for (int ot = 0; ot < 4; ot++)
        #pragma unroll
        for (int ks = 0; ks < 2; ks++)
            wa[ot][ks] = *(const bf16x8*)&Wo2[(ot * 16 + lr) * 64 + ks * 32 + lq * 8];
    float bl[4][4];
    #pragma unroll
    for (int ot = 0; ot < 4; ot++)
        #pragma unroll
        for (int r = 0; r < 4; r++) {
            int o = ot * 16 + lq * 4 + r;
            bl[ot][r] = (o < 63) ? b_out[o] : 0.f;
        }

    const f32x4 zf = {0.f, 0.f, 0.f, 0.f};
    int p0 = blockIdx.x * 256;
    int b = p0 / HWSZ;
    int hwb = p0 - b * HWSZ;
    for (int pt = 0; pt < 4; pt++) {
        int prow = (wv * 4 + pt) * 16;
        bf16x8 y0 = *(const bf16x8*)&Yl[prow + lr][lq * 8];
        bf16x8 y1 = *(const bf16x8*)&Yl[prow + lr][32 + lq * 8];
        f32x4 acc[4];
        #pragma unroll
        for (int ot = 0; ot < 4; ot++) {
            acc[ot] = __builtin_amdgcn_mfma_f32_16x16x32_bf16(wa[ot][0], y0, zf, 0, 0, 0);
            acc[ot] = __builtin_amdgcn_mfma_f32_16x16x32_bf16(wa[ot][1], y1, acc[ot], 0, 0, 0);
        }
        int hw = hwb + prow + lr;
        #pragma unroll
        for (int ot = 0; ot < 4; ot++) {
            #pragma unroll
            for (int r = 0; r < 4; r++) {
                int o = ot * 16 + lq * 4 + r;
                if (o < 63)
                    out[((size_t)(b * 63 + o)) * HWSZ + hw] = acc[ot][r] + bl[ot][r];
            }
        }
    }
}

extern "C" void kernel_launch(void* const* d_in, const int* in_sizes, int n_in,
                              void* d_out, int out_size, void* d_ws, size_t ws_size,
                              hipStream_t stream) {
    const float* x     = (const float*)d_in[0];
    const float* w_in  = (const float*)d_in[1];
    const float* b_in  = (const float*)d_in[2];
    const float* gamma = (const float*)d_in[3];
    const float* beta  = (const float*)d_in[4];
    const float* mean  = (const float*)d_in[5];
    const float* var   = (const float*)d_in[6];
    const float* w_out = (const float*)d_in[7];
    const float* b_out = (const float*)d_in[8];
    float* out = (float*)d_out;

    char* ws = (char*)d_ws;
    unsigned short* xp  = (unsigned short*)ws;                 // bf16 pair-interleaved [63pair][NPIX][2]
    unsigned short* ybA = (unsigned short*)(ws + 116121600);   // bf16 [NPIX][42]
    float*          bp  = (float*)(ws + 154845696);            // f32 [128]
    unsigned short* Wp2 = (unsigned short*)(ws + 154846208);   // bf16 [128][64] stride-64
    unsigned short* Wo2 = (unsigned short*)(ws + 154862592);   // bf16 [64][64] stride-64
    unsigned short* qt  = (unsigned short*)ws;                 // alias xp pairs (dead after k_winM)
    unsigned short* v1  = (unsigned short*)(ws + 19353600);
    unsigned short* ybB = (unsigned short*)(ws + 38707200);

    k_prep <<<49, 256, 0, stream>>>(w_in, b_in, gamma, beta, mean, var, w_out, bp, Wp2, Wo2);
    k_projM<<<1800, 256, 0, stream>>>(x, Wp2, bp, xp);
    k_winM <<<9216, 256, 0, stream>>>(xp, ybA);
    k_ax1  <<<1920, 256, 0, stream>>>(xp, qt, v1);
    k_ax2  <<<1920, 256, 0, stream>>>(qt, v1, ybB);
    k_outM <<<1800, 256, 0, stream>>>(ybA, ybB, Wo2, b_out, out);
}